// Round 6
// baseline (296.823 us; speedup 1.0000x reference)
//
#include <hip/hip_runtime.h>
#include <math.h>

#define NCLS 80           // background label
#define KDIM 128
#define INV_T 5.0f        // 1/TEMPERATURE
#define AST 136           // LDS stride (bf16): 128+8 pad; b128 reads -> 2-way only (free)
#define CSPLIT 8          // col-split: blocks per row tile

typedef __attribute__((ext_vector_type(4))) float  floatx4;
typedef __attribute__((ext_vector_type(8))) short  short8;

__device__ inline unsigned short f2bf(float x) {      // fp32 -> bf16 RNE
    unsigned int u = __float_as_uint(x);
    u += 0x7fffu + ((u >> 16) & 1u);
    return (unsigned short)(u >> 16);
}
__device__ inline ushort4 pack4(float4 v) {
    ushort4 r; r.x = f2bf(v.x); r.y = f2bf(v.y); r.z = f2bf(v.z); r.w = f2bf(v.w);
    return r;
}
__device__ inline float agload(const float* p) {
    return __hip_atomic_load(p, __ATOMIC_RELAXED, __HIP_MEMORY_SCOPE_AGENT);
}

// ---- setup (1 block, 1024 thr): compact novel indices, counts, init ticket --
// Zeroes its own counters in LDS -> no memset dispatch needed.
__global__ __launch_bounds__(1024) void setup_kernel(
    const int* __restrict__ labels, int M, int B,
    int* __restrict__ novel_idx, int* __restrict__ counters)
{
    __shared__ int cnt_n, cfg;
    const int tid  = threadIdx.x;
    const int lane = tid & 63;
    if (tid == 0) { cnt_n = 0; cfg = 0; }
    __syncthreads();

    int myfg = 0;
    for (int i0 = 0; i0 < M; i0 += 1024) {
        int i = i0 + tid;
        int lab = (i < M) ? labels[i] : NCLS;
        bool fg  = (lab != NCLS);
        bool isb = fg && (lab >= 0) && (lab < B);
        bool isn = fg && !isb;
        unsigned long long m = __ballot(isn);
        int wbase = 0;
        if (lane == 0 && m) wbase = atomicAdd(&cnt_n, __popcll(m));
        wbase = __shfl(wbase, 0);
        if (isn) novel_idx[wbase + __popcll(m & ((1ull << lane) - 1ull))] = i;
        myfg += fg ? 1 : 0;
    }
    #pragma unroll
    for (int off = 32; off; off >>= 1) myfg += __shfl_down(myfg, off);
    if (lane == 0 && myfg) atomicAdd(&cfg, myfg);
    __syncthreads();
    if (tid == 0) {
        counters[0] = cnt_n;   // n_novel
        counters[1] = cfg;     // numel (fg count)
        counters[3] = 0;       // ticket
    }
}

// ---- persistent MFMA GEMM + ticket-fused finalize ---------------------------
// 512 blocks = 64 row-tiles x 8 col-splits. A staged once; loop ct=cs,cs+8,...
// Novel tiles accumulate into LDS slices (race-free: one lane owns each slot);
// per-block slice written non-atomically to S1p/T1p[cs][M] (single writer, no
// zero-init needed). Proto tile (ct==ntiles, owned by cs==ntiles%8) writes
// EK/PKr directly. Last block (device ticket) computes the scalar loss with
// exact-fp32 pi.
__global__ __launch_bounds__(256, 2) void gemm_kernel(
    const float* __restrict__ feats, const float* __restrict__ protos,
    const int* __restrict__ labels, const int* __restrict__ novel_idx,
    int* __restrict__ counters, int M, int B,
    float* __restrict__ S1p, float* __restrict__ T1p,   // [CSPLIT][M]
    float* __restrict__ EK,  float* __restrict__ PKr,   // [M]
    float* __restrict__ out)
{
    __shared__ unsigned short As[128 * AST];   // 34816 B
    __shared__ unsigned short Bs[128 * AST];   // 34816 B
    __shared__ int   nidx[128];
    __shared__ float lS1[2][128], lT1[2][128]; // per col-wave novel accumulators
    __shared__ float lEK[2][128], lPK[2][128]; // per col-wave proto accumulators
    __shared__ double dred[4];
    __shared__ int   lastflag;

    const int tid = threadIdx.x;
    const int rt  = blockIdx.x >> 3;
    const int cs  = blockIdx.x & (CSPLIT - 1);
    const int row0 = rt * 128;
    const int Nn = counters[0];
    const int ntiles = (Nn + 127) >> 7;            // ct==ntiles -> proto tile
    const bool hasproto = ((ntiles & (CSPLIT - 1)) == cs);

    if (tid < 128) {
        lS1[0][tid] = 0.f; lS1[1][tid] = 0.f;
        lT1[0][tid] = 0.f; lT1[1][tid] = 0.f;
        lEK[0][tid] = 0.f; lEK[1][tid] = 0.f;
        lPK[0][tid] = 0.f; lPK[1][tid] = 0.f;
    }

    // ---- stage A once: 128 rows x 128 k, fp32 -> bf16 ----
    {
        const float4* f4 = (const float4*)(feats + (size_t)row0 * KDIM);
        #pragma unroll
        for (int p = 0; p < 16; ++p) {
            int chunk = p * 256 + tid;
            int r = chunk >> 5, kc = chunk & 31;
            *(ushort4*)&As[r * AST + kc * 4] = pack4(f4[r * 32 + kc]);
        }
    }

    const int wave = tid >> 6, lane = tid & 63;
    const int lr = lane & 15, quad = lane >> 4;
    const int wrow = (wave >> 1) * 64, wcol = (wave & 1) * 64;
    const int cw   = wave & 1;                     // col-wave slice id

    for (int ct = cs; ct <= ntiles; ct += CSPLIT) {
        const bool isproto = (ct == ntiles);
        __syncthreads();                           // prev iter's Bs/nidx reads done
        #pragma unroll
        for (int p = 0; p < 16; ++p) {
            int chunk = p * 256 + tid;
            int r = chunk >> 5, kc = chunk & 31;
            float4 v = make_float4(0.f, 0.f, 0.f, 0.f);
            if (isproto) {
                if (r < B) v = *(const float4*)(protos + (size_t)r * KDIM + kc * 4);
            } else {
                int jg = ct * 128 + r;
                if (jg < Nn)
                    v = *(const float4*)(feats + (size_t)novel_idx[jg] * KDIM + kc * 4);
            }
            *(ushort4*)&Bs[r * AST + kc * 4] = pack4(v);
        }
        if (tid < 128) {
            int nid = -1;
            if (isproto) { if (tid < B) nid = tid; }
            else { int jg = ct * 128 + tid; if (jg < Nn) nid = novel_idx[jg]; }
            nidx[tid] = nid;
        }
        __syncthreads();

        floatx4 acc[4][4];
        #pragma unroll
        for (int r = 0; r < 4; ++r)
            #pragma unroll
            for (int c = 0; c < 4; ++c)
                acc[r][c] = (floatx4){0.f, 0.f, 0.f, 0.f};

        #pragma unroll
        for (int ks = 0; ks < 4; ++ks) {
            short8 a[4], b[4];
            #pragma unroll
            for (int r = 0; r < 4; ++r)
                a[r] = *(const short8*)&As[(wrow + r * 16 + lr) * AST + ks * 32 + quad * 8];
            #pragma unroll
            for (int c = 0; c < 4; ++c)
                b[c] = *(const short8*)&Bs[(wcol + c * 16 + lr) * AST + ks * 32 + quad * 8];
            #pragma unroll
            for (int r = 0; r < 4; ++r)
                #pragma unroll
                for (int c = 0; c < 4; ++c)
                    acc[r][c] = __builtin_amdgcn_mfma_f32_16x16x32_bf16(
                        a[r], b[c], acc[r][c], 0, 0, 0);
        }

        // ---- epilogue: masked sums + 16-lane reduce -> LDS accumulators ----
        int ncol[4];
        #pragma unroll
        for (int c = 0; c < 4; ++c) ncol[c] = nidx[wcol + c * 16 + lr];

        #pragma unroll
        for (int r = 0; r < 4; ++r) {
            #pragma unroll
            for (int reg = 0; reg < 4; ++reg) {
                int lrow = wrow + r * 16 + quad * 4 + reg;   // C/D: row=quad*4+reg
                int irow = row0 + lrow;
                float se = 0.f, sr = 0.f;
                #pragma unroll
                for (int c = 0; c < 4; ++c) {
                    float sim = acc[r][c][reg] * INV_T;
                    bool valid = (ncol[c] >= 0) && (isproto || ncol[c] != irow);
                    if (valid) { se += __expf(sim); sr += sim; }
                }
                #pragma unroll
                for (int off = 1; off < 16; off <<= 1) {
                    se += __shfl_xor(se, off);
                    sr += __shfl_xor(sr, off);
                }
                if (lr == 0) {                    // slot (cw, lrow): unique owner lane
                    if (isproto) { lEK[cw][lrow] += se; lPK[cw][lrow] += sr; }
                    else         { lS1[cw][lrow] += se; lT1[cw][lrow] += sr; }
                }
            }
        }
    }

    __syncthreads();                              // all waves' LDS accumulation done
    if (tid < 128) {                              // single-writer global slices
        S1p[cs * M + row0 + tid] = lS1[0][tid] + lS1[1][tid];
        T1p[cs * M + row0 + tid] = lT1[0][tid] + lT1[1][tid];
        if (hasproto) {
            EK[row0 + tid]  = lEK[0][tid] + lEK[1][tid];
            PKr[row0 + tid] = lPK[0][tid] + lPK[1][tid];
        }
    }

    // ---- ticket: last arriving block finalizes ----
    __syncthreads();                              // drain this block's global stores
    if (tid == 0) {
        __threadfence();                          // release: wbl2 flushes this XCD's L2
        int old = atomicAdd(&counters[3], 1);
        lastflag = (old == (int)gridDim.x - 1) ? 1 : 0;
    }
    __syncthreads();
    if (!lastflag) return;

    __threadfence();                              // acquire (all finalize threads)
    const int numel = counters[1];
    const float cnt = (float)(Nn - 1);
    double part = 0.0;
    for (int i = tid; i < M; i += 256) {
        int lab = labels[i];
        bool fg  = (lab != NCLS);
        bool isb = fg && (lab >= 0) && (lab < B);
        bool isn = fg && !isb;
        if (isn) {
            if (Nn > 1) {
                float s1 = 0.f, t1 = 0.f;
                #pragma unroll
                for (int c = 0; c < CSPLIT; ++c) {
                    s1 += agload(&S1p[c * M + i]);
                    t1 += agload(&T1p[c * M + i]);
                }
                float pk = agload(&PKr[i]);
                part += (double)(-(t1 - cnt * logf(s1 + pk)) / cnt);
            }
        } else if (isb) {
            float s1 = 0.f;
            #pragma unroll
            for (int c = 0; c < CSPLIT; ++c) s1 += agload(&S1p[c * M + i]);
            float ek = agload(&EK[i]);
            // exact fp32 dot feats[i] . protos[lab]
            int sl = min(max(lab, 0), B - 1);
            const float4* fi = (const float4*)(feats + (size_t)i * KDIM);
            const float4* pr = (const float4*)(protos + (size_t)sl * KDIM);
            float d = 0.f;
            #pragma unroll 8
            for (int k = 0; k < KDIM / 4; ++k) {
                float4 a = fi[k], b = pr[k];
                d += a.x * b.x + a.y * b.y + a.z * b.z + a.w * b.w;
            }
            part += (double)(-(d * INV_T - logf(s1 + ek)));
        }
    }
    #pragma unroll
    for (int off = 32; off; off >>= 1) part += __shfl_down(part, off);
    if ((tid & 63) == 0) dred[tid >> 6] = part;
    __syncthreads();
    if (tid == 0)
        out[0] = (float)((dred[0] + dred[1] + dred[2] + dred[3]) / (double)numel);
}

extern "C" void kernel_launch(void* const* d_in, const int* in_sizes, int n_in,
                              void* d_out, int out_size, void* d_ws, size_t ws_size,
                              hipStream_t stream)
{
    const float* feats  = (const float*)d_in[0];
    const int*   labels = (const int*)d_in[1];
    const float* protos = (const float*)d_in[2];
    // d_in[3] proto_labels == arange(B); base membership == (label < B)

    const int M = in_sizes[1];
    const int B = in_sizes[3];

    char* ws = (char*)d_ws;
    int*   counters = (int*)ws;                   // 16 ints (incl. ticket)
    float* S1p = (float*)(ws + 64);               // [CSPLIT][M]
    float* T1p = S1p + CSPLIT * M;                // [CSPLIT][M]
    float* EK  = T1p + CSPLIT * M;                // [M]
    float* PKr = EK + M;                          // [M]
    int*   novel_idx = (int*)(PKr + M);           // [M]

    setup_kernel<<<1, 1024, 0, stream>>>(labels, M, B, novel_idx, counters);

    const int rtiles = (M + 127) / 128;           // 64
    gemm_kernel<<<rtiles * CSPLIT, 256, 0, stream>>>(
        feats, protos, labels, novel_idx, counters, M, B,
        S1p, T1p, EK, PKr, (float*)d_out);
}

// Round 7
// 152.407 us; speedup vs baseline: 1.9476x; 1.9476x over previous
//
#include <hip/hip_runtime.h>
#include <math.h>

#define NCLS 80           // background label
#define KDIM 128
#define INV_T 5.0f        // 1/TEMPERATURE
#define AST 136           // LDS stride (bf16): 128+8 pad; b128 reads -> 2-way only (free)
#define CSPLIT 8          // col-split: blocks per row tile

typedef __attribute__((ext_vector_type(4))) float  floatx4;
typedef __attribute__((ext_vector_type(8))) short  short8;

__device__ inline unsigned short f2bf(float x) {      // fp32 -> bf16 RNE
    unsigned int u = __float_as_uint(x);
    u += 0x7fffu + ((u >> 16) & 1u);
    return (unsigned short)(u >> 16);
}
__device__ inline ushort4 pack4(float4 v) {
    ushort4 r; r.x = f2bf(v.x); r.y = f2bf(v.y); r.z = f2bf(v.z); r.w = f2bf(v.w);
    return r;
}

// ---- setup (1 block, 1024 thr): compact novel indices, counts, init ticket --
__global__ __launch_bounds__(1024) void setup_kernel(
    const int* __restrict__ labels, int M, int B,
    int* __restrict__ novel_idx, int* __restrict__ counters)
{
    __shared__ int cnt_n, cfg;
    const int tid  = threadIdx.x;
    const int lane = tid & 63;
    if (tid == 0) { cnt_n = 0; cfg = 0; }
    __syncthreads();

    int myfg = 0;
    for (int i0 = 0; i0 < M; i0 += 1024) {
        int i = i0 + tid;
        int lab = (i < M) ? labels[i] : NCLS;
        bool fg  = (lab != NCLS);
        bool isb = fg && (lab >= 0) && (lab < B);
        bool isn = fg && !isb;
        unsigned long long m = __ballot(isn);
        int wbase = 0;
        if (lane == 0 && m) wbase = atomicAdd(&cnt_n, __popcll(m));
        wbase = __shfl(wbase, 0);
        if (isn) novel_idx[wbase + __popcll(m & ((1ull << lane) - 1ull))] = i;
        myfg += fg ? 1 : 0;
    }
    #pragma unroll
    for (int off = 32; off; off >>= 1) myfg += __shfl_down(myfg, off);
    if (lane == 0 && myfg) atomicAdd(&cfg, myfg);
    __syncthreads();
    if (tid == 0) {
        counters[0] = cnt_n;   // n_novel
        counters[1] = cfg;     // numel (fg count)
        counters[3] = 0;       // ticket
    }
}

// ---- persistent MFMA GEMM + ticket-fused finalize ---------------------------
// 512 blocks = 64 row-tiles x 8 col-splits; A staged once; ct = cs, cs+8, ...
// Novel tiles -> LDS accumulators (unique owner per slot) -> single-writer
// global slices S1p/T1p[cs][M] (no zero-init needed). Proto tile -> EK/PKr/PIv
// (pi from bf16 MFMA; round-4 measured absmax 0.0 with this). Last block
// (device ticket) finalizes with PLAIN cached loads after an acquire fence
// (buffer_inv) -- no agent-scope atomic loads (round-6: 230 us tail).
__global__ __launch_bounds__(256, 2) void gemm_kernel(
    const float* __restrict__ feats, const float* __restrict__ protos,
    const int* __restrict__ labels, const int* __restrict__ novel_idx,
    int* __restrict__ counters, int M, int B,
    float* __restrict__ S1p, float* __restrict__ T1p,   // [CSPLIT][M]
    float* __restrict__ EK,  float* __restrict__ PKr,   // [M]
    float* __restrict__ PIv,                            // [M]
    float* __restrict__ out)
{
    __shared__ unsigned short As[128 * AST];   // 34816 B
    __shared__ unsigned short Bs[128 * AST];   // 34816 B
    __shared__ int   nidx[128];
    __shared__ int   rlab[128];
    __shared__ float lS1[2][128], lT1[2][128];
    __shared__ float lEK[2][128], lPK[2][128], lPI[2][128];
    __shared__ double dred[4];
    __shared__ int   lastflag;

    const int tid = threadIdx.x;
    const int rt  = blockIdx.x >> 3;
    const int cs  = blockIdx.x & (CSPLIT - 1);
    const int row0 = rt * 128;
    const int Nn = counters[0];
    const int ntiles = (Nn + 127) >> 7;            // ct==ntiles -> proto tile
    const bool hasproto = ((ntiles & (CSPLIT - 1)) == cs);

    if (tid < 128) {
        lS1[0][tid] = 0.f; lS1[1][tid] = 0.f;
        lT1[0][tid] = 0.f; lT1[1][tid] = 0.f;
        lEK[0][tid] = 0.f; lEK[1][tid] = 0.f;
        lPK[0][tid] = 0.f; lPK[1][tid] = 0.f;
        lPI[0][tid] = 0.f; lPI[1][tid] = 0.f;
    }

    // ---- stage A once: 128 rows x 128 k, fp32 -> bf16; row labels ----
    {
        const float4* f4 = (const float4*)(feats + (size_t)row0 * KDIM);
        #pragma unroll
        for (int p = 0; p < 16; ++p) {
            int chunk = p * 256 + tid;
            int r = chunk >> 5, kc = chunk & 31;
            *(ushort4*)&As[r * AST + kc * 4] = pack4(f4[r * 32 + kc]);
        }
        if (tid < 128) rlab[tid] = labels[row0 + tid];
    }

    const int wave = tid >> 6, lane = tid & 63;
    const int lr = lane & 15, quad = lane >> 4;
    const int wrow = (wave >> 1) * 64, wcol = (wave & 1) * 64;
    const int cw   = wave & 1;                     // col-wave slice id

    for (int ct = cs; ct <= ntiles; ct += CSPLIT) {
        const bool isproto = (ct == ntiles);
        __syncthreads();                           // prev iter's Bs/nidx reads done
        #pragma unroll
        for (int p = 0; p < 16; ++p) {
            int chunk = p * 256 + tid;
            int r = chunk >> 5, kc = chunk & 31;
            float4 v = make_float4(0.f, 0.f, 0.f, 0.f);
            if (isproto) {
                if (r < B) v = *(const float4*)(protos + (size_t)r * KDIM + kc * 4);
            } else {
                int jg = ct * 128 + r;
                if (jg < Nn)
                    v = *(const float4*)(feats + (size_t)novel_idx[jg] * KDIM + kc * 4);
            }
            *(ushort4*)&Bs[r * AST + kc * 4] = pack4(v);
        }
        if (tid < 128) {
            int nid = -1;
            if (isproto) { if (tid < B) nid = tid; }
            else { int jg = ct * 128 + tid; if (jg < Nn) nid = novel_idx[jg]; }
            nidx[tid] = nid;
        }
        __syncthreads();

        floatx4 acc[4][4];
        #pragma unroll
        for (int r = 0; r < 4; ++r)
            #pragma unroll
            for (int c = 0; c < 4; ++c)
                acc[r][c] = (floatx4){0.f, 0.f, 0.f, 0.f};

        #pragma unroll
        for (int ks = 0; ks < 4; ++ks) {
            short8 a[4], b[4];
            #pragma unroll
            for (int r = 0; r < 4; ++r)
                a[r] = *(const short8*)&As[(wrow + r * 16 + lr) * AST + ks * 32 + quad * 8];
            #pragma unroll
            for (int c = 0; c < 4; ++c)
                b[c] = *(const short8*)&Bs[(wcol + c * 16 + lr) * AST + ks * 32 + quad * 8];
            #pragma unroll
            for (int r = 0; r < 4; ++r)
                #pragma unroll
                for (int c = 0; c < 4; ++c)
                    acc[r][c] = __builtin_amdgcn_mfma_f32_16x16x32_bf16(
                        a[r], b[c], acc[r][c], 0, 0, 0);
        }

        // ---- epilogue: masked sums + 16-lane reduce -> LDS accumulators ----
        int ncol[4];
        #pragma unroll
        for (int c = 0; c < 4; ++c) ncol[c] = nidx[wcol + c * 16 + lr];

        #pragma unroll
        for (int r = 0; r < 4; ++r) {
            #pragma unroll
            for (int reg = 0; reg < 4; ++reg) {
                int lrow = wrow + r * 16 + quad * 4 + reg;   // C/D: row=quad*4+reg
                int irow = row0 + lrow;
                if (isproto) {
                    int lab = rlab[lrow];
                    int sl  = min(max(lab, 0), B - 1);
                    float se = 0.f, sr = 0.f, spi = 0.f;
                    #pragma unroll
                    for (int c = 0; c < 4; ++c) {
                        float sim = acc[r][c][reg] * INV_T;
                        if (ncol[c] >= 0) {
                            se += __expf(sim); sr += sim;
                            if (ncol[c] == sl) spi += sim;
                        }
                    }
                    #pragma unroll
                    for (int off = 1; off < 16; off <<= 1) {
                        se  += __shfl_xor(se,  off);
                        sr  += __shfl_xor(sr,  off);
                        spi += __shfl_xor(spi, off);
                    }
                    if (lr == 0) {
                        lEK[cw][lrow] += se; lPK[cw][lrow] += sr; lPI[cw][lrow] += spi;
                    }
                } else {
                    float se = 0.f, sr = 0.f;
                    #pragma unroll
                    for (int c = 0; c < 4; ++c) {
                        float sim = acc[r][c][reg] * INV_T;
                        if (ncol[c] >= 0 && ncol[c] != irow) { se += __expf(sim); sr += sim; }
                    }
                    #pragma unroll
                    for (int off = 1; off < 16; off <<= 1) {
                        se += __shfl_xor(se, off);
                        sr += __shfl_xor(sr, off);
                    }
                    if (lr == 0) { lS1[cw][lrow] += se; lT1[cw][lrow] += sr; }
                }
            }
        }
    }

    __syncthreads();                              // all waves' LDS accumulation done
    if (tid < 128) {                              // single-writer global slices
        S1p[cs * M + row0 + tid] = lS1[0][tid] + lS1[1][tid];
        T1p[cs * M + row0 + tid] = lT1[0][tid] + lT1[1][tid];
        if (hasproto) {
            EK[row0 + tid]  = lEK[0][tid] + lEK[1][tid];
            PKr[row0 + tid] = lPK[0][tid] + lPK[1][tid];
            PIv[row0 + tid] = lPI[0][tid] + lPI[1][tid];
        }
    }

    // ---- ticket: last arriving block finalizes ----
    __syncthreads();                              // drains this block's stores (vmcnt)
    if (tid == 0) {
        __threadfence();                          // release: wbl2 flushes XCD L2
        int old = atomicAdd(&counters[3], 1);
        lastflag = (old == (int)gridDim.x - 1) ? 1 : 0;
    }
    __syncthreads();
    if (!lastflag) return;

    __threadfence();                              // acquire: buffer_inv -> plain loads safe
    const int numel = counters[1];
    const float cnt = (float)(Nn - 1);
    double part = 0.0;
    for (int i = tid; i < M; i += 256) {
        int lab = labels[i];
        bool fg  = (lab != NCLS);
        bool isb = fg && (lab >= 0) && (lab < B);
        bool isn = fg && !isb;
        if (isn) {
            if (Nn > 1) {
                float s1 = 0.f, t1 = 0.f;
                #pragma unroll
                for (int c = 0; c < CSPLIT; ++c) {
                    s1 += S1p[c * M + i];
                    t1 += T1p[c * M + i];
                }
                part += (double)(-(t1 - cnt * logf(s1 + PKr[i])) / cnt);
            }
        } else if (isb) {
            float s1 = 0.f;
            #pragma unroll
            for (int c = 0; c < CSPLIT; ++c) s1 += S1p[c * M + i];
            part += (double)(-(PIv[i] - logf(s1 + EK[i])));
        }
    }
    #pragma unroll
    for (int off = 32; off; off >>= 1) part += __shfl_down(part, off);
    if ((tid & 63) == 0) dred[tid >> 6] = part;
    __syncthreads();
    if (tid == 0)
        out[0] = (float)((dred[0] + dred[1] + dred[2] + dred[3]) / (double)numel);
}

extern "C" void kernel_launch(void* const* d_in, const int* in_sizes, int n_in,
                              void* d_out, int out_size, void* d_ws, size_t ws_size,
                              hipStream_t stream)
{
    const float* feats  = (const float*)d_in[0];
    const int*   labels = (const int*)d_in[1];
    const float* protos = (const float*)d_in[2];
    // d_in[3] proto_labels == arange(B); base membership == (label < B)

    const int M = in_sizes[1];
    const int B = in_sizes[3];

    char* ws = (char*)d_ws;
    int*   counters = (int*)ws;                   // 16 ints (incl. ticket)
    float* S1p = (float*)(ws + 64);               // [CSPLIT][M]
    float* T1p = S1p + CSPLIT * M;                // [CSPLIT][M]
    float* EK  = T1p + CSPLIT * M;                // [M]
    float* PKr = EK + M;                          // [M]
    float* PIv = PKr + M;                         // [M]
    int*   novel_idx = (int*)(PIv + M);           // [M]

    setup_kernel<<<1, 1024, 0, stream>>>(labels, M, B, novel_idx, counters);

    const int rtiles = (M + 127) / 128;           // 64
    gemm_kernel<<<rtiles * CSPLIT, 256, 0, stream>>>(
        feats, protos, labels, novel_idx, counters, M, B,
        S1p, T1p, EK, PKr, PIv, (float*)d_out);
}

// Round 8
// 108.906 us; speedup vs baseline: 2.7255x; 1.3994x over previous
//
#include <hip/hip_runtime.h>
#include <math.h>

#define NCLS 80           // background label
#define KDIM 128
#define INV_T 5.0f        // 1/TEMPERATURE
#define AST 136           // LDS stride (bf16): 128+8 pad; b128 reads -> 2-way only (free)
#define CSPLIT 8          // col-split: blocks per row tile

typedef __attribute__((ext_vector_type(4))) float  floatx4;
typedef __attribute__((ext_vector_type(8))) short  short8;

__device__ inline unsigned short f2bf(float x) {      // fp32 -> bf16 RNE
    unsigned int u = __float_as_uint(x);
    u += 0x7fffu + ((u >> 16) & 1u);
    return (unsigned short)(u >> 16);
}
__device__ inline ushort4 pack4(float4 v) {
    ushort4 r; r.x = f2bf(v.x); r.y = f2bf(v.y); r.z = f2bf(v.z); r.w = f2bf(v.w);
    return r;
}

// ---- setup (1 block, 1024 thr): compact novel indices, counts, zero out ----
__global__ __launch_bounds__(1024) void setup_kernel(
    const int* __restrict__ labels, int M, int B,
    int* __restrict__ novel_idx, int* __restrict__ counters,
    float* __restrict__ out)
{
    __shared__ int cnt_n, cfg;
    const int tid  = threadIdx.x;
    const int lane = tid & 63;
    if (tid == 0) { cnt_n = 0; cfg = 0; out[0] = 0.f; }
    __syncthreads();

    int myfg = 0;
    for (int i0 = 0; i0 < M; i0 += 1024) {
        int i = i0 + tid;
        int lab = (i < M) ? labels[i] : NCLS;
        bool fg  = (lab != NCLS);
        bool isb = fg && (lab >= 0) && (lab < B);
        bool isn = fg && !isb;
        unsigned long long m = __ballot(isn);
        int wbase = 0;
        if (lane == 0 && m) wbase = atomicAdd(&cnt_n, __popcll(m));
        wbase = __shfl(wbase, 0);
        if (isn) novel_idx[wbase + __popcll(m & ((1ull << lane) - 1ull))] = i;
        myfg += fg ? 1 : 0;
    }
    #pragma unroll
    for (int off = 32; off; off >>= 1) myfg += __shfl_down(myfg, off);
    if (lane == 0 && myfg) atomicAdd(&cfg, myfg);
    __syncthreads();
    if (tid == 0) {
        counters[0] = cnt_n;   // n_novel
        counters[1] = cfg;     // numel (fg count)
    }
}

// ---- persistent MFMA GEMM: 512 blocks = 64 row-tiles x 8 col-splits ---------
// A staged once per block; loop ct = cs, cs+8, ..., ntiles (last = proto tile).
// Novel tiles -> LDS accumulators (unique owner lane per slot) -> single-writer
// global slices S1p/T1p[cs][M] (no zero-init, no atomics, no fences -- the
// kernel boundary provides visibility to the finalize dispatch; round-7's
// per-block __threadfence/ticket cost ~60 us).
// Proto tile -> EK/PKr/PIv (pi from bf16 MFMA; rounds 4/7 measured absmax 0.0).
__global__ __launch_bounds__(256, 2) void gemm_kernel(
    const float* __restrict__ feats, const float* __restrict__ protos,
    const int* __restrict__ labels, const int* __restrict__ novel_idx,
    const int* __restrict__ counters, int M, int B,
    float* __restrict__ S1p, float* __restrict__ T1p,   // [CSPLIT][M]
    float* __restrict__ EK,  float* __restrict__ PKr,   // [M]
    float* __restrict__ PIv)                            // [M]
{
    __shared__ unsigned short As[128 * AST];   // 34816 B
    __shared__ unsigned short Bs[128 * AST];   // 34816 B
    __shared__ int   nidx[128];
    __shared__ int   rlab[128];
    __shared__ float lS1[2][128], lT1[2][128];
    __shared__ float lEK[2][128], lPK[2][128], lPI[2][128];

    const int tid = threadIdx.x;
    const int rt  = blockIdx.x >> 3;
    const int cs  = blockIdx.x & (CSPLIT - 1);
    const int row0 = rt * 128;
    const int Nn = counters[0];
    const int ntiles = (Nn + 127) >> 7;            // ct==ntiles -> proto tile
    const bool hasproto = ((ntiles & (CSPLIT - 1)) == cs);

    if (tid < 128) {
        lS1[0][tid] = 0.f; lS1[1][tid] = 0.f;
        lT1[0][tid] = 0.f; lT1[1][tid] = 0.f;
        lEK[0][tid] = 0.f; lEK[1][tid] = 0.f;
        lPK[0][tid] = 0.f; lPK[1][tid] = 0.f;
        lPI[0][tid] = 0.f; lPI[1][tid] = 0.f;
    }

    // ---- stage A once: 128 rows x 128 k, fp32 -> bf16; row labels ----
    {
        const float4* f4 = (const float4*)(feats + (size_t)row0 * KDIM);
        #pragma unroll
        for (int p = 0; p < 16; ++p) {
            int chunk = p * 256 + tid;
            int r = chunk >> 5, kc = chunk & 31;
            *(ushort4*)&As[r * AST + kc * 4] = pack4(f4[r * 32 + kc]);
        }
        if (tid < 128) rlab[tid] = labels[row0 + tid];
    }

    const int wave = tid >> 6, lane = tid & 63;
    const int lr = lane & 15, quad = lane >> 4;
    const int wrow = (wave >> 1) * 64, wcol = (wave & 1) * 64;
    const int cw   = wave & 1;                     // col-wave slice id

    for (int ct = cs; ct <= ntiles; ct += CSPLIT) {
        const bool isproto = (ct == ntiles);
        __syncthreads();                           // prev iter's Bs/nidx reads done
        #pragma unroll
        for (int p = 0; p < 16; ++p) {
            int chunk = p * 256 + tid;
            int r = chunk >> 5, kc = chunk & 31;
            float4 v = make_float4(0.f, 0.f, 0.f, 0.f);
            if (isproto) {
                if (r < B) v = *(const float4*)(protos + (size_t)r * KDIM + kc * 4);
            } else {
                int jg = ct * 128 + r;
                if (jg < Nn)
                    v = *(const float4*)(feats + (size_t)novel_idx[jg] * KDIM + kc * 4);
            }
            *(ushort4*)&Bs[r * AST + kc * 4] = pack4(v);
        }
        if (tid < 128) {
            int nid = -1;
            if (isproto) { if (tid < B) nid = tid; }
            else { int jg = ct * 128 + tid; if (jg < Nn) nid = novel_idx[jg]; }
            nidx[tid] = nid;
        }
        __syncthreads();

        floatx4 acc[4][4];
        #pragma unroll
        for (int r = 0; r < 4; ++r)
            #pragma unroll
            for (int c = 0; c < 4; ++c)
                acc[r][c] = (floatx4){0.f, 0.f, 0.f, 0.f};

        #pragma unroll
        for (int ks = 0; ks < 4; ++ks) {
            short8 a[4], b[4];
            #pragma unroll
            for (int r = 0; r < 4; ++r)
                a[r] = *(const short8*)&As[(wrow + r * 16 + lr) * AST + ks * 32 + quad * 8];
            #pragma unroll
            for (int c = 0; c < 4; ++c)
                b[c] = *(const short8*)&Bs[(wcol + c * 16 + lr) * AST + ks * 32 + quad * 8];
            #pragma unroll
            for (int r = 0; r < 4; ++r)
                #pragma unroll
                for (int c = 0; c < 4; ++c)
                    acc[r][c] = __builtin_amdgcn_mfma_f32_16x16x32_bf16(
                        a[r], b[c], acc[r][c], 0, 0, 0);
        }

        // ---- epilogue: masked sums + 16-lane reduce -> LDS accumulators ----
        int ncol[4];
        #pragma unroll
        for (int c = 0; c < 4; ++c) ncol[c] = nidx[wcol + c * 16 + lr];

        #pragma unroll
        for (int r = 0; r < 4; ++r) {
            #pragma unroll
            for (int reg = 0; reg < 4; ++reg) {
                int lrow = wrow + r * 16 + quad * 4 + reg;   // C/D: row=quad*4+reg
                int irow = row0 + lrow;
                if (isproto) {
                    int lab = rlab[lrow];
                    int sl  = min(max(lab, 0), B - 1);
                    float se = 0.f, sr = 0.f, spi = 0.f;
                    #pragma unroll
                    for (int c = 0; c < 4; ++c) {
                        float sim = acc[r][c][reg] * INV_T;
                        if (ncol[c] >= 0) {
                            se += __expf(sim); sr += sim;
                            if (ncol[c] == sl) spi += sim;
                        }
                    }
                    #pragma unroll
                    for (int off = 1; off < 16; off <<= 1) {
                        se  += __shfl_xor(se,  off);
                        sr  += __shfl_xor(sr,  off);
                        spi += __shfl_xor(spi, off);
                    }
                    if (lr == 0) {
                        lEK[cw][lrow] += se; lPK[cw][lrow] += sr; lPI[cw][lrow] += spi;
                    }
                } else {
                    float se = 0.f, sr = 0.f;
                    #pragma unroll
                    for (int c = 0; c < 4; ++c) {
                        float sim = acc[r][c][reg] * INV_T;
                        if (ncol[c] >= 0 && ncol[c] != irow) { se += __expf(sim); sr += sim; }
                    }
                    #pragma unroll
                    for (int off = 1; off < 16; off <<= 1) {
                        se += __shfl_xor(se, off);
                        sr += __shfl_xor(sr, off);
                    }
                    if (lr == 0) { lS1[cw][lrow] += se; lT1[cw][lrow] += sr; }
                }
            }
        }
    }

    __syncthreads();                              // all waves' LDS accumulation done
    if (tid < 128) {                              // single-writer global slices
        S1p[cs * M + row0 + tid] = lS1[0][tid] + lS1[1][tid];
        T1p[cs * M + row0 + tid] = lT1[0][tid] + lT1[1][tid];
        if (hasproto) {
            EK[row0 + tid]  = lEK[0][tid] + lEK[1][tid];
            PKr[row0 + tid] = lPK[0][tid] + lPK[1][tid];
            PIv[row0 + tid] = lPI[0][tid] + lPI[1][tid];
        }
    }
}

// ---- finalize (32 blocks x 256, one row/thread): per-row losses -> scalar ---
__global__ __launch_bounds__(256) void finalize_kernel(
    const int* __restrict__ labels,
    const float* __restrict__ S1p, const float* __restrict__ T1p,
    const float* __restrict__ EK,  const float* __restrict__ PKr,
    const float* __restrict__ PIv, const int* __restrict__ counters,
    int M, int B, float* __restrict__ out)
{
    __shared__ double dred[4];
    const int tid = threadIdx.x;
    const int i   = blockIdx.x * 256 + tid;
    const int Nn = counters[0], numel = counters[1];
    const float cnt = (float)(Nn - 1);

    double part = 0.0;
    if (i < M) {
        int lab = labels[i];
        bool fg  = (lab != NCLS);
        bool isb = fg && (lab >= 0) && (lab < B);
        bool isn = fg && !isb;
        if (isn) {
            if (Nn > 1) {
                float s1 = 0.f, t1 = 0.f;
                #pragma unroll
                for (int c = 0; c < CSPLIT; ++c) {
                    s1 += S1p[c * M + i];
                    t1 += T1p[c * M + i];
                }
                part = (double)(-(t1 - cnt * logf(s1 + PKr[i])) / cnt);
            }
        } else if (isb) {
            float s1 = 0.f;
            #pragma unroll
            for (int c = 0; c < CSPLIT; ++c) s1 += S1p[c * M + i];
            part = (double)(-(PIv[i] - logf(s1 + EK[i])));
        }
    }
    #pragma unroll
    for (int off = 32; off; off >>= 1) part += __shfl_down(part, off);
    if ((tid & 63) == 0) dred[tid >> 6] = part;
    __syncthreads();
    if (tid == 0) {
        double s = dred[0] + dred[1] + dred[2] + dred[3];
        atomicAdd(out, (float)(s / (double)numel));
    }
}

extern "C" void kernel_launch(void* const* d_in, const int* in_sizes, int n_in,
                              void* d_out, int out_size, void* d_ws, size_t ws_size,
                              hipStream_t stream)
{
    const float* feats  = (const float*)d_in[0];
    const int*   labels = (const int*)d_in[1];
    const float* protos = (const float*)d_in[2];
    // d_in[3] proto_labels == arange(B); base membership == (label < B)

    const int M = in_sizes[1];
    const int B = in_sizes[3];

    char* ws = (char*)d_ws;
    int*   counters = (int*)ws;                   // 16 ints
    float* S1p = (float*)(ws + 64);               // [CSPLIT][M]
    float* T1p = S1p + CSPLIT * M;                // [CSPLIT][M]
    float* EK  = T1p + CSPLIT * M;                // [M]
    float* PKr = EK + M;                          // [M]
    float* PIv = PKr + M;                         // [M]
    int*   novel_idx = (int*)(PIv + M);           // [M]

    setup_kernel<<<1, 1024, 0, stream>>>(labels, M, B, novel_idx, counters,
                                         (float*)d_out);

    const int rtiles = (M + 127) / 128;           // 64
    gemm_kernel<<<rtiles * CSPLIT, 256, 0, stream>>>(
        feats, protos, labels, novel_idx, counters, M, B,
        S1p, T1p, EK, PKr, PIv);

    finalize_kernel<<<(M + 255) / 256, 256, 0, stream>>>(
        labels, S1p, T1p, EK, PKr, PIv, counters, M, B, (float*)d_out);
}